// Round 15
// baseline (697.136 us; speedup 1.0000x reference)
//
#include <hip/hip_runtime.h>
#include <math.h>

// GCN on MI355X. N=200000 nodes, E=6400000 edges.
// R29: R28's phase-cut was net-neutral-to-negative (L2 fused slab 4.8MB > L2
// 4MB -> FETCH 140MB; boundary-count tuning exhausted at ~387). New lever:
// FUSE LAYER-1 INTO k_build. k_build is latency-bound with idle pipes
// (occ 33%, VALU 26%, HBM 12%); its read-2 already visits every edge record.
// Add per-record p1[src] load (2.4MB L2-resident) + 3x ds_add_f32 into
// qacc[dl*5+c] (no-return, stride 5 per R21 bank lesson); per-dst epilogue
// applies W1->tanh, writes p2. di comes free from htot (= exact degree).
// Prereq: p1 before build -> deg[] via fire-and-forget global atomicAdd
// fused into k_count (R19: global hist is cheap); p1/p2 moved OUT of the
// stg overlap region (ws ~65MB < 76 proven). Deletes the L1 gather launch
// (~42us, incl. a full 25.6MB adj re-read).
// Gathers: R26 verified config (L2 2ph @b13, L3 3ph @b8/b17, UN=4).
// NO cooperative launches (R27 lesson). MESSAGES STAY FP32 (R7 bisect).

static constexpr int NN = 200000;
static constexpr int NE = 6400000;
static constexpr int BK = 256;

static constexpr int SUBW  = 512;                    // scat/count bin width (d>>9)
static constexpr int NBA   = (NN + SUBW - 1) / SUBW; // 391 bins
static constexpr int HDS   = 256;                    // dsts per build half
static constexpr int BKB   = 512;                    // build threads
static constexpr int NBB   = ((NBA + 7) / 8) * 8 * 2;// 784 swizzled build blocks
static constexpr int LCAP  = 8832;                   // half staging cap (+7 sigma)
static constexpr int NBL   = 1024;                   // count/scatter blocks
static constexpr int BKC   = 512;                    // threads in count/scatter
static constexpr int SEG   = (NE + NBL - 1) / NBL;   // 6250 edges per block (exact)
static constexpr int T1    = 65536;                  // range cuts
static constexpr int T2    = 106496;
static constexpr int T3    = 139264;

static constexpr int S     = 4;                      // lanes per node in gathers
static constexpr int LOGS  = 2;

// ---------- build pass 1: per-block bin histogram + global per-node degree ----------
__global__ void __launch_bounds__(BKC) k_count(const int* __restrict__ dstI,
                                               int* __restrict__ hist,
                                               int* __restrict__ deg, int e) {
  __shared__ int cnt[NBA];
  for (int t = threadIdx.x; t < NBA; t += BKC) cnt[t] = 0;
  __syncthreads();
  int blk = blockIdx.x;
  int st = blk * SEG, en = st + SEG; if (en > e) en = e;
  int i = st + (int)threadIdx.x;
  for (; i + 3 * BKC < en; i += 4 * BKC) {
    int d0 = __builtin_nontemporal_load(dstI + i);
    int d1 = __builtin_nontemporal_load(dstI + i + BKC);
    int d2 = __builtin_nontemporal_load(dstI + i + 2 * BKC);
    int d3 = __builtin_nontemporal_load(dstI + i + 3 * BKC);
    atomicAdd(&cnt[d0 >> 9], 1);
    atomicAdd(&cnt[d1 >> 9], 1);
    atomicAdd(&cnt[d2 >> 9], 1);
    atomicAdd(&cnt[d3 >> 9], 1);
    atomicAdd(&deg[d0], 1);              // fire-and-forget global (R19-cheap)
    atomicAdd(&deg[d1], 1);
    atomicAdd(&deg[d2], 1);
    atomicAdd(&deg[d3], 1);
  }
  for (; i < en; i += BKC) {
    int d = __builtin_nontemporal_load(dstI + i);
    atomicAdd(&cnt[d >> 9], 1);
    atomicAdd(&deg[d], 1);
  }
  __syncthreads();
  for (int t = threadIdx.x; t < NBA; t += BKC) hist[(size_t)t * NBL + blk] = cnt[t];
}

__global__ void k_zero(int* __restrict__ p, int n) {
  int i = blockIdx.x * blockDim.x + threadIdx.x;
  if (i < n) p[i] = 0;
}

// ---------- build pass 2a: per-bin exclusive scan over 1024 blocks ----------
__global__ void __launch_bounds__(256) k_scanrow(int* __restrict__ hist,
                                                 int* __restrict__ tot) {
  __shared__ int s0[256], s1[256];
  int b = blockIdx.x, t = threadIdx.x;
  int* row = hist + (size_t)b * NBL;
  uint4 vv = ((const uint4*)row)[t];           // row 16B-aligned (NBL%4==0)
  int v0 = (int)vv.x, v1 = (int)vv.y, v2 = (int)vv.z, v3 = (int)vv.w;
  int s = v0 + v1 + v2 + v3;
  s0[t] = s;
  __syncthreads();
  int* a = s0; int* bb = s1;
  for (int o = 1; o < 256; o <<= 1) {
    bb[t] = a[t] + ((t >= o) ? a[t - o] : 0);
    __syncthreads();
    int* tmp = a; a = bb; bb = tmp;
  }
  int ex = a[t] - s;                 // exclusive over quads
  uint4 w;
  w.x = (unsigned)ex;
  w.y = (unsigned)(ex + v0);
  w.z = (unsigned)(ex + v0 + v1);
  w.w = (unsigned)(ex + v0 + v1 + v2);
  ((uint4*)row)[t] = w;
  if (t == 255) tot[b] = a[t];
}

// ---------- build pass 2b: exclusive scan of bin totals -> dense bases ----------
__global__ void k_scanbin(const int* __restrict__ tot, int* __restrict__ sbase) {
  __shared__ int s0[512], s1[512];
  int t = threadIdx.x;
  int v = (t < NBA) ? tot[t] : 0;
  s0[t] = v;
  __syncthreads();
  int* a = s0; int* b = s1;
  for (int o = 1; o < 512; o <<= 1) {
    b[t] = a[t] + ((t >= o) ? a[t - o] : 0);
    __syncthreads();
    int* tmp = a; a = b; b = tmp;
  }
  if (t < NBA) sbase[t] = a[t] - v;
  if (t == NBA - 1) sbase[NBA] = a[t];   // == E
}

// ---------- build pass 3: LDS-staged scatter, per-bin coalesced-run flush ----------
__global__ void __launch_bounds__(BKC) k_scat(const int* __restrict__ srcI,
                                              const int* __restrict__ dstI,
                                              const int* __restrict__ hist,
                                              const int* __restrict__ tot,
                                              const int* __restrict__ sbase,
                                              unsigned* __restrict__ stg, int e) {
  __shared__ int pref[NBA];
  __shared__ int cur[NBA];
  __shared__ unsigned lstg[SEG];
  __shared__ int s0[BKC], s1[BKC];
  int blk = blockIdx.x;
  int t = threadIdx.x;
  int h0 = 0, lc = 0;
  if (t < NBA) {
    h0 = hist[(size_t)t * NBL + blk];
    int h1 = (blk < NBL - 1) ? hist[(size_t)t * NBL + blk + 1] : tot[t];
    lc = h1 - h0;
  }
  s0[t] = lc;
  __syncthreads();
  int* a = s0; int* b = s1;
  for (int o = 1; o < BKC; o <<= 1) {
    b[t] = a[t] + ((t >= o) ? a[t - o] : 0);
    __syncthreads();
    int* tmp = a; a = b; b = tmp;
  }
  if (t < NBA) {
    int ex = a[t] - lc;
    pref[t] = ex;
    cur[t] = ex;
  }
  __syncthreads();
  int st = blk * SEG, en = st + SEG; if (en > e) en = e;
  int i = st + t;
  for (; i + 3 * BKC < en; i += 4 * BKC) {
    int s0v = __builtin_nontemporal_load(srcI + i);
    int d0 = __builtin_nontemporal_load(dstI + i);
    int s1v = __builtin_nontemporal_load(srcI + i + BKC);
    int d1 = __builtin_nontemporal_load(dstI + i + BKC);
    int s2v = __builtin_nontemporal_load(srcI + i + 2 * BKC);
    int d2 = __builtin_nontemporal_load(dstI + i + 2 * BKC);
    int s3v = __builtin_nontemporal_load(srcI + i + 3 * BKC);
    int d3 = __builtin_nontemporal_load(dstI + i + 3 * BKC);
    int p0 = atomicAdd(&cur[d0 >> 9], 1);
    int p1 = atomicAdd(&cur[d1 >> 9], 1);
    int p2 = atomicAdd(&cur[d2 >> 9], 1);
    int p3 = atomicAdd(&cur[d3 >> 9], 1);
    lstg[p0] = ((unsigned)(d0 & (SUBW - 1)) << 18) | (unsigned)s0v;
    lstg[p1] = ((unsigned)(d1 & (SUBW - 1)) << 18) | (unsigned)s1v;
    lstg[p2] = ((unsigned)(d2 & (SUBW - 1)) << 18) | (unsigned)s2v;
    lstg[p3] = ((unsigned)(d3 & (SUBW - 1)) << 18) | (unsigned)s3v;
  }
  for (; i < en; i += BKC) {
    int sv = __builtin_nontemporal_load(srcI + i);
    int d = __builtin_nontemporal_load(dstI + i);
    int p = atomicAdd(&cur[d >> 9], 1);
    lstg[p] = ((unsigned)(d & (SUBW - 1)) << 18) | (unsigned)sv;
  }
  __syncthreads();
  // flush: thread t copies bin t's run; same-thread consecutive stores merge
  if (t < NBA && lc > 0) {
    int lo = pref[t];
    int g = sbase[t] + h0;
    for (int j = 0; j < lc; ++j) stg[g + j] = lstg[lo + j];
  }
}

// ---------- pass 4: half-bin 4-range build + FUSED LAYER-1 aggregation ----------
// During read-2, each in-half record also accumulates p1[src] into qacc[dl]
// (ds_add_f32 fire-and-forget). Epilogue: q += p1[node] (self-loop), W1->tanh,
// write p2. di = rsqrt(1+htot) (htot == exact degree of node).
__global__ void __launch_bounds__(BKB) k_build(const unsigned* __restrict__ stg,
                                               const int* __restrict__ sbase,
                                               const float* __restrict__ p1,
                                               const float* __restrict__ W1,
                                               const float* __restrict__ b1,
                                               int* __restrict__ rowptr,
                                               int* __restrict__ adj,
                                               int* __restrict__ b8,
                                               int* __restrict__ b13,
                                               int* __restrict__ b17,
                                               float* __restrict__ p2) {
  __shared__ unsigned hist2[HDS * 5];      // 5.1 KB: [dl_h][range], slot 4 pad
  __shared__ int htot[HDS];
  __shared__ int s0[HDS], s1[HDS];
  __shared__ unsigned astg[LCAP];          // 35.3 KB staged adj
  __shared__ float qacc[HDS * 5];          // 5.1 KB fused-L1 accum (stride 5)
  __shared__ float sW1[18], sb1[6];
  __shared__ int beforeCnt;
  int g = blockIdx.x;
  int x = g & 7, j = g >> 3;
  int h = j & 1;
  int bin = (j >> 1) * 8 + x;              // halves of bin -> same XCD (g%8)
  if (bin >= NBA) return;
  int base = sbase[bin];
  int m = sbase[bin + 1] - base;
  size_t off = (size_t)base;
  if (g == 0 && threadIdx.x == 0) rowptr[NN] = sbase[NBA];   // == E
  for (int t = threadIdx.x; t < HDS * 5; t += BKB) { hist2[t] = 0; qacc[t] = 0.f; }
  if (threadIdx.x < 18) sW1[threadIdx.x] = W1[threadIdx.x];
  if (threadIdx.x >= 32 && threadIdx.x < 38) sb1[threadIdx.x - 32] = b1[threadIdx.x - 32];
  if (threadIdx.x == 0) beforeCnt = 0;
  __syncthreads();
  // read 1: 4-range histogram of this half; count half-0 recs for base_eff
  int myBefore = 0;
  for (int k = threadIdx.x; k < m; k += BKB) {
    unsigned rec = stg[off + k];
    int dl = (int)(rec >> 18);
    if ((dl >> 8) == h) {
      int src = (int)(rec & 0x3FFFFu);
      int r = (src >= T1) + (src >= T2) + (src >= T3);
      atomicAdd(&hist2[(dl & (HDS - 1)) * 5 + r], 1u);
    } else if (h == 1) {
      ++myBefore;
    }
  }
  if (myBefore) atomicAdd(&beforeCnt, myBefore);
  __syncthreads();
  // per-dl exclusive scan over 4 ranges (threads 0..255)
  if (threadIdx.x < HDS) {
    int dl = threadIdx.x;
    unsigned run = 0;
#pragma unroll
    for (int r = 0; r < 4; ++r) {
      unsigned c = hist2[dl * 5 + r];
      hist2[dl * 5 + r] = run;
      run += c;
    }
    htot[dl] = (int)run;
    s0[dl] = (int)run;
  }
  __syncthreads();
  // block inclusive scan over 256 dls (ping-pong, 8 iters)
  int* a = s0; int* bb = s1;
  for (int o2 = 1; o2 < HDS; o2 <<= 1) {
    if (threadIdx.x < HDS) {
      int t = threadIdx.x;
      bb[t] = a[t] + ((t >= o2) ? a[t - o2] : 0);
    }
    __syncthreads();
    int* tmp = a; a = bb; bb = tmp;
  }
  int mytot = a[HDS - 1];
  int base_eff = base + beforeCnt;
  if (threadIdx.x < HDS) {
    int t = threadIdx.x;
    int node = bin * SUBW + h * HDS + t;
    int ex = a[t] - htot[t];
    if (node < NN) {
      rowptr[node] = base_eff + ex;
      b8[node]  = base_eff + ex + (int)hist2[t * 5 + 1];   // exclusive prefixes
      b13[node] = base_eff + ex + (int)hist2[t * 5 + 2];
      b17[node] = base_eff + ex + (int)hist2[t * 5 + 3];
    }
    bb[t] = ex;
  }
  __syncthreads();
  // read 2 (L2-hot): range-ordered scatter into LDS + fused-L1 accumulation
  for (int k = threadIdx.x; k < m; k += BKB) {
    unsigned rec = stg[off + k];
    int dl = (int)(rec >> 18);
    if ((dl >> 8) != h) continue;
    int src = (int)(rec & 0x3FFFFu);
    int r = (src >= T1) + (src >= T2) + (src >= T3);
    int dlh = dl & (HDS - 1);
    int p = bb[dlh] + (int)atomicAdd(&hist2[dlh * 5 + r], 1u);
    if (p < LCAP) astg[p] = (unsigned)src;
    else adj[base_eff + p] = src;
    float3 v = *(const float3*)(p1 + 3 * (size_t)src);   // L2-resident 2.4MB
    atomicAdd(&qacc[dlh * 5 + 0], v.x);                  // ds_add_f32, no return
    atomicAdd(&qacc[dlh * 5 + 1], v.y);
    atomicAdd(&qacc[dlh * 5 + 2], v.z);
  }
  __syncthreads();
  // coalesced adj flush (zero write amp)
  int mm = mytot < LCAP ? mytot : LCAP;
  for (int k = threadIdx.x; k < mm; k += BKB) adj[base_eff + k] = (int)astg[k];
  // fused Layer-1 epilogue: q += self, W1 -> tanh, p2 = di*act (24B rows)
  if (threadIdx.x < HDS) {
    int t = threadIdx.x;
    int node = bin * SUBW + h * HDS + t;
    if (node < NN) {
      float q0 = qacc[t * 5 + 0] + p1[3 * (size_t)node + 0];
      float q1 = qacc[t * 5 + 1] + p1[3 * (size_t)node + 1];
      float q2 = qacc[t * 5 + 2] + p1[3 * (size_t)node + 2];
      float di = rsqrtf(1.0f + (float)htot[t]);
      float o[6];
#pragma unroll
      for (int jj = 0; jj < 6; ++jj) {
        float s = fmaf(q0, sW1[jj], fmaf(q1, sW1[6 + jj], q2 * sW1[12 + jj]));
        o[jj] = di * tanhf(fmaf(di, s, sb1[jj]));
      }
      float* po = p2 + 6 * (size_t)node;
      *(float2*)(po)     = make_float2(o[0], o[1]);
      *(float2*)(po + 2) = make_float2(o[2], o[3]);
      *(float2*)(po + 4) = make_float2(o[4], o[5]);
    }
  }
}

// dinv + p1 = dinv*x in one pass (12B rows); deg from global histogram
__global__ void k_prep(const float* __restrict__ x, const int* __restrict__ deg,
                       float* __restrict__ dinv, float* __restrict__ p1, int n) {
  int i = blockIdx.x * blockDim.x + threadIdx.x;
  if (i >= n) return;
  float di = rsqrtf(1.0f + (float)deg[i]);
  dinv[i] = di;
  float3 v;
  v.x = di * x[3 * (size_t)i];
  v.y = di * x[3 * (size_t)i + 1];
  v.z = di * x[3 * (size_t)i + 2];
  *(float3*)(p1 + 3 * (size_t)i) = v;
}

// ---------- packed-row load/accumulate/store (RW floats per row) ----------
template <int RW> struct RowT;
template <> struct RowT<6> {
  struct T { float2 a, b, c; };       // 24B rows, 8B-aligned
  static __device__ inline T ld(const float* __restrict__ p) {
    T t; t.a = *(const float2*)p; t.b = *(const float2*)(p + 2); t.c = *(const float2*)(p + 4);
    return t;
  }
  static __device__ inline void add(float* __restrict__ a, const T& v) {
    a[0] += v.a.x; a[1] += v.a.y; a[2] += v.b.x; a[3] += v.b.y; a[4] += v.c.x; a[5] += v.c.y;
  }
  static __device__ inline void st(float* __restrict__ p, const float* __restrict__ a) {
    *(float2*)(p)     = make_float2(a[0], a[1]);
    *(float2*)(p + 2) = make_float2(a[2], a[3]);
    *(float2*)(p + 4) = make_float2(a[4], a[5]);
  }
};
template <> struct RowT<12> {
  struct T { float4 a, b, c; };       // 48B rows, 16B-aligned bases
  static __device__ inline T ld(const float* __restrict__ p) {
    T t; t.a = *(const float4*)p; t.b = *(const float4*)(p + 4); t.c = *(const float4*)(p + 8);
    return t;
  }
  static __device__ inline void add(float* __restrict__ a, const T& v) {
    a[0] += v.a.x; a[1] += v.a.y; a[2] += v.a.z; a[3] += v.a.w;
    a[4] += v.b.x; a[5] += v.b.y; a[6] += v.b.z; a[7] += v.b.w;
    a[8] += v.c.x; a[9] += v.c.y; a[10] += v.c.z; a[11] += v.c.w;
  }
  static __device__ inline void st(float* __restrict__ p, const float* __restrict__ a) {
    *(float4*)(p)     = make_float4(a[0], a[1], a[2], a[3]);
    *(float4*)(p + 4) = make_float4(a[4], a[5], a[6], a[7]);
    *(float4*)(p + 8) = make_float4(a[8], a[9], a[10], a[11]);
  }
};

// ---------- slot-strided gather over [st,en), unroll UN, adj prefetch 1 ahead ----------
template <int RW, int UN>
__device__ inline void gather_p(const int* __restrict__ adj, int st, int en,
                                const float* __restrict__ pin, float* __restrict__ acc,
                                int slot) {
  using RT = RowT<RW>;
  using T = typename RT::T;
  int k = st + slot;
  if (k + (UN - 1) * S < en) {
    int a[UN];
#pragma unroll
    for (int u = 0; u < UN; ++u) a[u] = adj[k + u * S];
    for (;;) {
      int kn = k + UN * S;
      bool more = (kn + (UN - 1) * S < en);
      int b[UN];
#pragma unroll
      for (int u = 0; u < UN; ++u) b[u] = 0;
      if (more) {
#pragma unroll
        for (int u = 0; u < UN; ++u) b[u] = adj[kn + u * S];
      }
      T v[UN];
#pragma unroll
      for (int u = 0; u < UN; ++u) v[u] = RT::ld(pin + (size_t)a[u] * RW);
#pragma unroll
      for (int u = 0; u < UN; ++u) RT::add(acc, v[u]);
      k = kn;
      if (!more) break;
#pragma unroll
      for (int u = 0; u < UN; ++u) a[u] = b[u];
    }
  }
  for (; k < en; k += S) {
    T v = RT::ld(pin + (size_t)adj[k] * RW);
    RT::add(acc, v);
  }
}

// 4-lane butterfly: all lanes end with the full sum
template <int FIN>
__device__ inline void group_reduce(float* __restrict__ acc) {
#pragma unroll
  for (int j = 0; j < FIN; ++j) {
    acc[j] += __shfl_xor(acc[j], 1);
    acc[j] += __shfl_xor(acc[j], 2);
  }
}

// ---------- phased gather: one src-range slab per kernel launch ----------
// FIRST: acc = self-loop; else acc = reload packed partial (slot 0 holds it).
template <int RW, bool FIRST>
__global__ void __launch_bounds__(BK, 8) k_gphase(
    const int* __restrict__ adj, const int* __restrict__ stA,
    const int* __restrict__ enB, const float* __restrict__ pin,
    float* __restrict__ accb, int n) {
  int g = blockIdx.x * blockDim.x + threadIdx.x;
  int i = g >> LOGS;
  int slot = g & (S - 1);
  if (i >= n) return;
  float acc[RW] = {};
  if (slot == 0) {
    if (FIRST) {
      typename RowT<RW>::T v = RowT<RW>::ld(pin + (size_t)i * RW);  // self-loop
      RowT<RW>::add(acc, v);
    } else {
      typename RowT<RW>::T v = RowT<RW>::ld(accb + (size_t)i * RW); // partial
      RowT<RW>::add(acc, v);
    }
  }
  gather_p<RW, 4>(adj, stA[i], enB[i], pin, acc, slot);
  group_reduce<RW>(acc);
  if (slot == 0) RowT<RW>::st(accb + (size_t)i * RW, acc);
}

// ---------- final phase: last slab + epilogue ----------
// MODE 1: l2norm+tanh -> pout (48B rows for FOUT=12)
// MODE 2: l2norm -> Wc -> l2norm -> out (13 floats)
template <int RW, int FOUT, int MODE>
__global__ void __launch_bounds__(BK, 6) k_gphase_last(
    const int* __restrict__ adj, const int* __restrict__ stA,
    const int* __restrict__ rowptr, const float* __restrict__ pin,
    const float* __restrict__ W, const float* __restrict__ bias,
    const float* __restrict__ Wc, const float* __restrict__ bc,
    const float* __restrict__ dinv, const float* __restrict__ accb,
    float* __restrict__ out, int n) {
  constexpr int FC = 13;
  __shared__ float sW[RW * FOUT];
  __shared__ float sb[FOUT];
  __shared__ float sWc[MODE == 2 ? FOUT * FC : 1];
  __shared__ float sbc[MODE == 2 ? FC : 1];
  for (int t = threadIdx.x; t < RW * FOUT; t += BK) sW[t] = W[t];
  if (threadIdx.x < FOUT) sb[threadIdx.x] = bias[threadIdx.x];
  if (MODE == 2) {
    for (int t = threadIdx.x; t < FOUT * FC; t += BK) sWc[t] = Wc[t];
    if (threadIdx.x < FC) sbc[threadIdx.x] = bc[threadIdx.x];
  }
  __syncthreads();
  int g = blockIdx.x * blockDim.x + threadIdx.x;
  int i = g >> LOGS;
  int slot = g & (S - 1);
  if (i >= n) return;
  float acc[RW] = {};
  if (slot == 0) {
    typename RowT<RW>::T v = RowT<RW>::ld(accb + (size_t)i * RW);   // partial
    RowT<RW>::add(acc, v);
  }
  gather_p<RW, 4>(adj, stA[i], rowptr[i + 1], pin, acc, slot);
  group_reduce<RW>(acc);
  float di = dinv[i];
  float h[FOUT];
  float ss = 0.f;
#pragma unroll
  for (int j = 0; j < FOUT; ++j) {
    float s = 0.f;
#pragma unroll
    for (int kk = 0; kk < RW; ++kk) s = fmaf(acc[kk], sW[kk * FOUT + j], s);
    float t = fmaf(di, s, sb[j]);
    h[j] = t;
    ss += t * t;
  }
  float inv = 1.f / fmaxf(sqrtf(ss), 1e-12f);
  if (MODE == 1) {
    float o[FOUT];
#pragma unroll
    for (int j = 0; j < FOUT; ++j) o[j] = di * tanhf(h[j] * inv);
    if (slot == 0) {
      float* po = out + (size_t)i * FOUT;                  // 48B rows (FOUT=12)
      *(float4*)(po)     = make_float4(o[0], o[1], o[2], o[3]);
      *(float4*)(po + 4) = make_float4(o[4], o[5], o[6], o[7]);
      *(float4*)(po + 8) = make_float4(o[8], o[9], o[10], o[11]);
    }
  } else {
    float v[FC];
    float ss2 = 0.f;
#pragma unroll
    for (int j = 0; j < FC; ++j) {
      float s = sbc[j];
#pragma unroll
      for (int kk = 0; kk < FOUT; ++kk) s = fmaf(h[kk] * inv, sWc[kk * FC + j], s);
      v[j] = s;
      ss2 += s * s;
    }
    float inv2 = 1.f / fmaxf(sqrtf(ss2), 1e-12f);
    if (slot == 0) {
#pragma unroll
      for (int j = 0; j < FC; ++j) out[(size_t)i * FC + j] = v[j] * inv2;
    }
  }
}

extern "C" void kernel_launch(void* const* d_in, const int* in_sizes, int n_in,
                              void* d_out, int out_size, void* d_ws, size_t ws_size,
                              hipStream_t stream) {
  const float* x  = (const float*)d_in[0];
  const int*   ei = (const int*)d_in[1];
  const float* W1 = (const float*)d_in[2];
  const float* b1 = (const float*)d_in[3];
  const float* W2 = (const float*)d_in[4];
  const float* b2 = (const float*)d_in[5];
  const float* W3 = (const float*)d_in[6];
  const float* b3 = (const float*)d_in[7];
  const float* Wc = (const float*)d_in[8];
  const float* bc = (const float*)d_in[9];
  float* out = (float*)d_out;

  const int n = NN;
  const int e = NE;
  const int* srcI = ei;       // row 0
  const int* dstI = ei + e;   // row 1

  // Workspace (words):
  //   dinv[N] | rowptr[N+8] | sbase[512] | tot[512] | hist[NBA*NBL] | adj[E]
  //   | b8[N] | b13[N] | b17[N] | deg[N] | p1[3N] | p2[6N] | pad->64B
  //   | R { stg[E] during build, then p3[12N] | accb[12N] }
  // p1/p2 are OUTSIDE R: written before/during build while stg is live.
  // Total ~= 65 MB (<= 76 MB proven safe).
  float* ws = (float*)d_ws;
  float* dinv  = ws;
  int* rowptr  = (int*)(ws + n);            // N+8 (uses N+1, padded)
  int* sbase   = rowptr + n + 8;            // NBA+1 used
  int* tot     = sbase + 512;
  int* hist    = tot + 512;                 // NBA * NBL (16B-aligned)
  int* adj     = hist + NBA * NBL;
  int* b8      = adj + e;
  int* b13     = b8 + n;
  int* b17     = b13 + n;
  int* deg     = b17 + n;
  float* p1    = (float*)(deg + n);         // 3N
  float* p2    = p1 + (size_t)3 * n;        // 6N
  size_t roff = (size_t)n + (n + 8) + 512 + 512 + (size_t)NBA * NBL + e
              + 3 * (size_t)n + (size_t)n + 3 * (size_t)n + 6 * (size_t)n;
  roff = (roff + 15) & ~(size_t)15;         // round to 16 words = 64B
  float* R     = ws + roff;
  unsigned* stg = (unsigned*)R;             // dense E words during build
  float* p3   = R;                          // 12N (after build)
  float* accb = R + (size_t)12 * n;         // 12N packed partials

  const int gn  = (n + BK - 1) / BK;
  const int gnS = (n * S + BK - 1) / BK;    // 3125 blocks

  // --- CSR build + fused L1: deg+count -> scans -> prep -> scat -> build ---
  k_zero<<<(n + BK - 1) / BK, BK, 0, stream>>>(deg, n);
  k_count<<<NBL, BKC, 0, stream>>>(dstI, hist, deg, e);
  k_scanrow<<<NBA, 256, 0, stream>>>(hist, tot);
  k_scanbin<<<1, 512, 0, stream>>>(tot, sbase);
  k_prep<<<gn, BK, 0, stream>>>(x, deg, dinv, p1, n);
  k_scat<<<NBL, BKC, 0, stream>>>(srcI, dstI, hist, tot, sbase, stg, e);
  k_build<<<NBB, BKB, 0, stream>>>(stg, sbase, p1, W1, b1, rowptr, adj,
                                   b8, b13, b17, p2);

  // --- Layer 2 (p2 = 4.8 MB): 2 phases, cut at b13 (slabs fit L2) ---
  k_gphase<6, true><<<gnS, BK, 0, stream>>>(adj, rowptr, b13, p2, accb, n);
  k_gphase_last<6, 12, 1><<<gnS, BK, 0, stream>>>(adj, b13, rowptr, p2, W2, b2,
                                                  Wc, bc, dinv, accb, p3, n);

  // --- Layer 3 + classifier (p3 = 9.6 MB): 3 phases, cuts at b8/b17 ---
  k_gphase<12, true><<<gnS, BK, 0, stream>>>(adj, rowptr, b8, p3, accb, n);
  k_gphase<12, false><<<gnS, BK, 0, stream>>>(adj, b8, b17, p3, accb, n);
  k_gphase_last<12, 24, 2><<<gnS, BK, 0, stream>>>(adj, b17, rowptr, p3, W3, b3,
                                                   Wc, bc, dinv, accb, out, n);
}

// Round 16
// 388.850 us; speedup vs baseline: 1.7928x; 1.7928x over previous
//
#include <hip/hip_runtime.h>
#include <math.h>

// GCN on MI355X. N=200000 nodes, E=6400000 edges.
// R30: RESTORE R26 (387.4us, best verified). R29's Layer-1 fusion failed on
// two measured counts: (1) per-node global atomicAdd deg[] = 212MB write amp
// (random 4B RMW across XCDs; fire-and-forget removes latency, not line
// traffic); (2) fused k_build ~200us -- k_build cost is LINEAR in LDS
// atomics/record (1 atomic = 53us, 4 = ~200). Structural floors now mapped:
//   build ~115us (two ~50us per-record-LDS-atomic passes + streaming),
//   gathers ~235us (latency-bound; phase-boundary tuning is +-5us noise
//   per R18/R28; coop fusion unusable in harness per R27).
// Chain: count -> scanrow -> scanbin -> LDS-staged scat (R25) -> half-bin
// 4-range build (R26) -> prep -> L1 1ph -> L2 2ph @b13 -> L3 3ph @b8/b17.
// MESSAGES STAY FP32 (R7: bf16 fails 0.21).

static constexpr int NN = 200000;
static constexpr int NE = 6400000;
static constexpr int BK = 256;

static constexpr int SUBW  = 512;                    // scat/count bin width (d>>9)
static constexpr int NBA   = (NN + SUBW - 1) / SUBW; // 391 bins
static constexpr int HDS   = 256;                    // dsts per build half
static constexpr int BKB   = 512;                    // build threads
static constexpr int NBB   = ((NBA + 7) / 8) * 8 * 2;// 784 swizzled build blocks
static constexpr int LCAP  = 8832;                   // half staging cap (+7 sigma)
static constexpr int NBL   = 1024;                   // count/scatter blocks
static constexpr int BKC   = 512;                    // threads in count/scatter
static constexpr int SEG   = (NE + NBL - 1) / NBL;   // 6250 edges per block (exact)
static constexpr int T1    = 65536;                  // range cuts
static constexpr int T2    = 106496;
static constexpr int T3    = 139264;

static constexpr int S     = 4;                      // lanes per node in gathers
static constexpr int LOGS  = 2;

// ---------- build pass 1: per-block LDS histogram (no return deps) ----------
__global__ void __launch_bounds__(BKC) k_count(const int* __restrict__ dstI,
                                               int* __restrict__ hist, int e) {
  __shared__ int cnt[NBA];
  for (int t = threadIdx.x; t < NBA; t += BKC) cnt[t] = 0;
  __syncthreads();
  int blk = blockIdx.x;
  int st = blk * SEG, en = st + SEG; if (en > e) en = e;
  int i = st + (int)threadIdx.x;
  for (; i + 3 * BKC < en; i += 4 * BKC) {
    int d0 = __builtin_nontemporal_load(dstI + i);
    int d1 = __builtin_nontemporal_load(dstI + i + BKC);
    int d2 = __builtin_nontemporal_load(dstI + i + 2 * BKC);
    int d3 = __builtin_nontemporal_load(dstI + i + 3 * BKC);
    atomicAdd(&cnt[d0 >> 9], 1);
    atomicAdd(&cnt[d1 >> 9], 1);
    atomicAdd(&cnt[d2 >> 9], 1);
    atomicAdd(&cnt[d3 >> 9], 1);
  }
  for (; i < en; i += BKC) {
    int d = __builtin_nontemporal_load(dstI + i);
    atomicAdd(&cnt[d >> 9], 1);
  }
  __syncthreads();
  for (int t = threadIdx.x; t < NBA; t += BKC) hist[(size_t)t * NBL + blk] = cnt[t];
}

// ---------- build pass 2a: per-bin exclusive scan over 1024 blocks ----------
__global__ void __launch_bounds__(256) k_scanrow(int* __restrict__ hist,
                                                 int* __restrict__ tot) {
  __shared__ int s0[256], s1[256];
  int b = blockIdx.x, t = threadIdx.x;
  int* row = hist + (size_t)b * NBL;
  uint4 vv = ((const uint4*)row)[t];           // row 16B-aligned (NBL%4==0)
  int v0 = (int)vv.x, v1 = (int)vv.y, v2 = (int)vv.z, v3 = (int)vv.w;
  int s = v0 + v1 + v2 + v3;
  s0[t] = s;
  __syncthreads();
  int* a = s0; int* bb = s1;
  for (int o = 1; o < 256; o <<= 1) {
    bb[t] = a[t] + ((t >= o) ? a[t - o] : 0);
    __syncthreads();
    int* tmp = a; a = bb; bb = tmp;
  }
  int ex = a[t] - s;                 // exclusive over quads
  uint4 w;
  w.x = (unsigned)ex;
  w.y = (unsigned)(ex + v0);
  w.z = (unsigned)(ex + v0 + v1);
  w.w = (unsigned)(ex + v0 + v1 + v2);
  ((uint4*)row)[t] = w;
  if (t == 255) tot[b] = a[t];
}

// ---------- build pass 2b: exclusive scan of bin totals -> dense bases ----------
__global__ void k_scanbin(const int* __restrict__ tot, int* __restrict__ sbase) {
  __shared__ int s0[512], s1[512];
  int t = threadIdx.x;
  int v = (t < NBA) ? tot[t] : 0;
  s0[t] = v;
  __syncthreads();
  int* a = s0; int* b = s1;
  for (int o = 1; o < 512; o <<= 1) {
    b[t] = a[t] + ((t >= o) ? a[t - o] : 0);
    __syncthreads();
    int* tmp = a; a = b; b = tmp;
  }
  if (t < NBA) sbase[t] = a[t] - v;
  if (t == NBA - 1) sbase[NBA] = a[t];   // == E
}

// ---------- build pass 3: LDS-staged scatter, per-bin coalesced-run flush ----------
__global__ void __launch_bounds__(BKC) k_scat(const int* __restrict__ srcI,
                                              const int* __restrict__ dstI,
                                              const int* __restrict__ hist,
                                              const int* __restrict__ tot,
                                              const int* __restrict__ sbase,
                                              unsigned* __restrict__ stg, int e) {
  __shared__ int pref[NBA];
  __shared__ int cur[NBA];
  __shared__ unsigned lstg[SEG];
  __shared__ int s0[BKC], s1[BKC];
  int blk = blockIdx.x;
  int t = threadIdx.x;
  int h0 = 0, lc = 0;
  if (t < NBA) {
    h0 = hist[(size_t)t * NBL + blk];
    int h1 = (blk < NBL - 1) ? hist[(size_t)t * NBL + blk + 1] : tot[t];
    lc = h1 - h0;
  }
  s0[t] = lc;
  __syncthreads();
  int* a = s0; int* b = s1;
  for (int o = 1; o < BKC; o <<= 1) {
    b[t] = a[t] + ((t >= o) ? a[t - o] : 0);
    __syncthreads();
    int* tmp = a; a = b; b = tmp;
  }
  if (t < NBA) {
    int ex = a[t] - lc;
    pref[t] = ex;
    cur[t] = ex;
  }
  __syncthreads();
  int st = blk * SEG, en = st + SEG; if (en > e) en = e;
  int i = st + t;
  for (; i + 3 * BKC < en; i += 4 * BKC) {
    int s0v = __builtin_nontemporal_load(srcI + i);
    int d0 = __builtin_nontemporal_load(dstI + i);
    int s1v = __builtin_nontemporal_load(srcI + i + BKC);
    int d1 = __builtin_nontemporal_load(dstI + i + BKC);
    int s2v = __builtin_nontemporal_load(srcI + i + 2 * BKC);
    int d2 = __builtin_nontemporal_load(dstI + i + 2 * BKC);
    int s3v = __builtin_nontemporal_load(srcI + i + 3 * BKC);
    int d3 = __builtin_nontemporal_load(dstI + i + 3 * BKC);
    int p0 = atomicAdd(&cur[d0 >> 9], 1);
    int p1 = atomicAdd(&cur[d1 >> 9], 1);
    int p2 = atomicAdd(&cur[d2 >> 9], 1);
    int p3 = atomicAdd(&cur[d3 >> 9], 1);
    lstg[p0] = ((unsigned)(d0 & (SUBW - 1)) << 18) | (unsigned)s0v;
    lstg[p1] = ((unsigned)(d1 & (SUBW - 1)) << 18) | (unsigned)s1v;
    lstg[p2] = ((unsigned)(d2 & (SUBW - 1)) << 18) | (unsigned)s2v;
    lstg[p3] = ((unsigned)(d3 & (SUBW - 1)) << 18) | (unsigned)s3v;
  }
  for (; i < en; i += BKC) {
    int sv = __builtin_nontemporal_load(srcI + i);
    int d = __builtin_nontemporal_load(dstI + i);
    int p = atomicAdd(&cur[d >> 9], 1);
    lstg[p] = ((unsigned)(d & (SUBW - 1)) << 18) | (unsigned)sv;
  }
  __syncthreads();
  // flush: thread t copies bin t's run; same-thread consecutive stores merge
  if (t < NBA && lc > 0) {
    int lo = pref[t];
    int g = sbase[t] + h0;
    for (int j = 0; j < lc; ++j) stg[g + j] = lstg[lo + j];
  }
}

// ---------- pass 4: half-bin 4-range build, LDS-staged coalesced flush ----------
// XCD-swizzled: halves of one bin share an XCD (8 apart in dispatch) -> bin
// slab L2-hot for half 1. Half h base = bin base + (# half-0 recs) tallied
// during the hist read. hist2 = [dl][range] (stride 5 pads banks).
__global__ void __launch_bounds__(BKB) k_build(const unsigned* __restrict__ stg,
                                               const int* __restrict__ sbase,
                                               int* __restrict__ rowptr,
                                               int* __restrict__ adj,
                                               int* __restrict__ b8,
                                               int* __restrict__ b13,
                                               int* __restrict__ b17) {
  __shared__ unsigned hist2[HDS * 5];      // 5.1 KB: [dl_h][range], slot 4 pad
  __shared__ int htot[HDS];
  __shared__ int s0[HDS], s1[HDS];
  __shared__ unsigned astg[LCAP];          // 35.3 KB staged adj (total ~43.6KB)
  __shared__ int beforeCnt;
  int g = blockIdx.x;
  int x = g & 7, j = g >> 3;
  int h = j & 1;
  int bin = (j >> 1) * 8 + x;              // halves of bin -> same XCD (g%8)
  if (bin >= NBA) return;
  int base = sbase[bin];
  int m = sbase[bin + 1] - base;
  size_t off = (size_t)base;
  if (g == 0 && threadIdx.x == 0) rowptr[NN] = sbase[NBA];   // == E
  for (int t = threadIdx.x; t < HDS * 5; t += BKB) hist2[t] = 0;
  if (threadIdx.x == 0) beforeCnt = 0;
  __syncthreads();
  // read 1: 4-range histogram of this half; count half-0 recs for base_eff
  int myBefore = 0;
  for (int k = threadIdx.x; k < m; k += BKB) {
    unsigned rec = stg[off + k];
    int dl = (int)(rec >> 18);
    if ((dl >> 8) == h) {
      int src = (int)(rec & 0x3FFFFu);
      int r = (src >= T1) + (src >= T2) + (src >= T3);
      atomicAdd(&hist2[(dl & (HDS - 1)) * 5 + r], 1u);
    } else if (h == 1) {
      ++myBefore;
    }
  }
  if (myBefore) atomicAdd(&beforeCnt, myBefore);
  __syncthreads();
  // per-dl exclusive scan over 4 ranges (threads 0..255)
  if (threadIdx.x < HDS) {
    int dl = threadIdx.x;
    unsigned run = 0;
#pragma unroll
    for (int r = 0; r < 4; ++r) {
      unsigned c = hist2[dl * 5 + r];
      hist2[dl * 5 + r] = run;
      run += c;
    }
    htot[dl] = (int)run;
    s0[dl] = (int)run;
  }
  __syncthreads();
  // block inclusive scan over 256 dls (ping-pong, 8 iters)
  int* a = s0; int* bb = s1;
  for (int o2 = 1; o2 < HDS; o2 <<= 1) {
    if (threadIdx.x < HDS) {
      int t = threadIdx.x;
      bb[t] = a[t] + ((t >= o2) ? a[t - o2] : 0);
    }
    __syncthreads();
    int* tmp = a; a = bb; bb = tmp;
  }
  int mytot = a[HDS - 1];
  int base_eff = base + beforeCnt;
  if (threadIdx.x < HDS) {
    int t = threadIdx.x;
    int node = bin * SUBW + h * HDS + t;
    int ex = a[t] - htot[t];
    if (node < NN) {
      rowptr[node] = base_eff + ex;
      b8[node]  = base_eff + ex + (int)hist2[t * 5 + 1];   // exclusive prefixes
      b13[node] = base_eff + ex + (int)hist2[t * 5 + 2];
      b17[node] = base_eff + ex + (int)hist2[t * 5 + 3];
    }
    bb[t] = ex;
  }
  __syncthreads();
  // read 2 (L2-hot): range-ordered scatter into LDS staging (overflow direct)
  for (int k = threadIdx.x; k < m; k += BKB) {
    unsigned rec = stg[off + k];
    int dl = (int)(rec >> 18);
    if ((dl >> 8) != h) continue;
    int src = (int)(rec & 0x3FFFFu);
    int r = (src >= T1) + (src >= T2) + (src >= T3);
    int p = bb[dl & (HDS - 1)] + (int)atomicAdd(&hist2[(dl & (HDS - 1)) * 5 + r], 1u);
    if (p < LCAP) astg[p] = (unsigned)src;
    else adj[base_eff + p] = src;
  }
  __syncthreads();
  // coalesced flush: zero write amplification
  int mm = mytot < LCAP ? mytot : LCAP;
  for (int k = threadIdx.x; k < mm; k += BKB) adj[base_eff + k] = (int)astg[k];
}

// dinv + p1 = dinv*x in one pass (12B rows)
__global__ void k_prep(const float* __restrict__ x, const int* __restrict__ rowptr,
                       float* __restrict__ dinv, float* __restrict__ p1, int n) {
  int i = blockIdx.x * blockDim.x + threadIdx.x;
  if (i >= n) return;
  float di = rsqrtf(1.0f + (float)(rowptr[i + 1] - rowptr[i]));
  dinv[i] = di;
  float3 v;
  v.x = di * x[3 * (size_t)i];
  v.y = di * x[3 * (size_t)i + 1];
  v.z = di * x[3 * (size_t)i + 2];
  *(float3*)(p1 + 3 * (size_t)i) = v;
}

// ---------- packed-row load/accumulate/store (RW floats per row) ----------
template <int RW> struct RowT;
template <> struct RowT<3> {
  using T = float3;   // 12B rows
  static __device__ inline T ld(const float* __restrict__ p) { return *(const float3*)p; }
  static __device__ inline void add(float* __restrict__ a, const T& v) {
    a[0] += v.x; a[1] += v.y; a[2] += v.z;
  }
  static __device__ inline void st(float* __restrict__ p, const float* __restrict__ a) {
    *(float3*)p = make_float3(a[0], a[1], a[2]);
  }
};
template <> struct RowT<6> {
  struct T { float2 a, b, c; };       // 24B rows, 8B-aligned
  static __device__ inline T ld(const float* __restrict__ p) {
    T t; t.a = *(const float2*)p; t.b = *(const float2*)(p + 2); t.c = *(const float2*)(p + 4);
    return t;
  }
  static __device__ inline void add(float* __restrict__ a, const T& v) {
    a[0] += v.a.x; a[1] += v.a.y; a[2] += v.b.x; a[3] += v.b.y; a[4] += v.c.x; a[5] += v.c.y;
  }
  static __device__ inline void st(float* __restrict__ p, const float* __restrict__ a) {
    *(float2*)(p)     = make_float2(a[0], a[1]);
    *(float2*)(p + 2) = make_float2(a[2], a[3]);
    *(float2*)(p + 4) = make_float2(a[4], a[5]);
  }
};
template <> struct RowT<12> {
  struct T { float4 a, b, c; };       // 48B rows, 16B-aligned bases
  static __device__ inline T ld(const float* __restrict__ p) {
    T t; t.a = *(const float4*)p; t.b = *(const float4*)(p + 4); t.c = *(const float4*)(p + 8);
    return t;
  }
  static __device__ inline void add(float* __restrict__ a, const T& v) {
    a[0] += v.a.x; a[1] += v.a.y; a[2] += v.a.z; a[3] += v.a.w;
    a[4] += v.b.x; a[5] += v.b.y; a[6] += v.b.z; a[7] += v.b.w;
    a[8] += v.c.x; a[9] += v.c.y; a[10] += v.c.z; a[11] += v.c.w;
  }
  static __device__ inline void st(float* __restrict__ p, const float* __restrict__ a) {
    *(float4*)(p)     = make_float4(a[0], a[1], a[2], a[3]);
    *(float4*)(p + 4) = make_float4(a[4], a[5], a[6], a[7]);
    *(float4*)(p + 8) = make_float4(a[8], a[9], a[10], a[11]);
  }
};

// ---------- slot-strided gather over [st,en), unroll UN, adj prefetch 1 ahead ----------
template <int RW, int UN>
__device__ inline void gather_p(const int* __restrict__ adj, int st, int en,
                                const float* __restrict__ pin, float* __restrict__ acc,
                                int slot) {
  using RT = RowT<RW>;
  using T = typename RT::T;
  int k = st + slot;
  if (k + (UN - 1) * S < en) {
    int a[UN];
#pragma unroll
    for (int u = 0; u < UN; ++u) a[u] = adj[k + u * S];
    for (;;) {
      int kn = k + UN * S;
      bool more = (kn + (UN - 1) * S < en);
      int b[UN];
#pragma unroll
      for (int u = 0; u < UN; ++u) b[u] = 0;
      if (more) {
#pragma unroll
        for (int u = 0; u < UN; ++u) b[u] = adj[kn + u * S];
      }
      T v[UN];
#pragma unroll
      for (int u = 0; u < UN; ++u) v[u] = RT::ld(pin + (size_t)a[u] * RW);
#pragma unroll
      for (int u = 0; u < UN; ++u) RT::add(acc, v[u]);
      k = kn;
      if (!more) break;
#pragma unroll
      for (int u = 0; u < UN; ++u) a[u] = b[u];
    }
  }
  for (; k < en; k += S) {
    T v = RT::ld(pin + (size_t)adj[k] * RW);
    RT::add(acc, v);
  }
}

// 4-lane butterfly: all lanes end with the full sum
template <int FIN>
__device__ inline void group_reduce(float* __restrict__ acc) {
#pragma unroll
  for (int j = 0; j < FIN; ++j) {
    acc[j] += __shfl_xor(acc[j], 1);
    acc[j] += __shfl_xor(acc[j], 2);
  }
}

// ---------- single-phase fused gather (layer 1 only; slab fits L2) ----------
template <int RW, int FOUT, int MODE>
__global__ void __launch_bounds__(BK, 8) k_gather_fused(
    const int* __restrict__ adj, const int* __restrict__ rowptr,
    const float* __restrict__ pin, const float* __restrict__ W,
    const float* __restrict__ bias, const float* __restrict__ dinv,
    float* __restrict__ pout, int n) {
  __shared__ float sW[RW * FOUT];
  __shared__ float sb[FOUT];
  for (int t = threadIdx.x; t < RW * FOUT; t += BK) sW[t] = W[t];
  if (threadIdx.x < FOUT) sb[threadIdx.x] = bias[threadIdx.x];
  __syncthreads();
  int g = blockIdx.x * blockDim.x + threadIdx.x;
  int i = g >> LOGS;
  int slot = g & (S - 1);
  if (i >= n) return;
  float acc[RW] = {};
  if (slot == 0) {                                  // self-loop on slot 0
    typename RowT<RW>::T v = RowT<RW>::ld(pin + (size_t)i * RW);
    RowT<RW>::add(acc, v);
  }
  gather_p<RW, 4>(adj, rowptr[i], rowptr[i + 1], pin, acc, slot);
  group_reduce<RW>(acc);
  float di = dinv[i];
  float h[FOUT];
  float ss = 0.f;
#pragma unroll
  for (int j = 0; j < FOUT; ++j) {
    float s = 0.f;
#pragma unroll
    for (int kk = 0; kk < RW; ++kk) s = fmaf(acc[kk], sW[kk * FOUT + j], s);
    float t = fmaf(di, s, sb[j]);
    h[j] = t;
    ss += t * t;
  }
  float o[FOUT];
  if (MODE == 0) {
#pragma unroll
    for (int j = 0; j < FOUT; ++j) o[j] = di * tanhf(h[j]);
  } else {
    float inv = 1.f / fmaxf(sqrtf(ss), 1e-12f);
#pragma unroll
    for (int j = 0; j < FOUT; ++j) o[j] = di * tanhf(h[j] * inv);
  }
  if (slot == 0) {
    float* po = pout + (size_t)i * FOUT;
    if (MODE == 0) {                                 // 24B rows: 3x float2
      *(float2*)(po)     = make_float2(o[0], o[1]);
      *(float2*)(po + 2) = make_float2(o[2], o[3]);
      *(float2*)(po + 4) = make_float2(o[4], o[5]);
    } else {                                         // 48B rows: 3x float4
      *(float4*)(po)     = make_float4(o[0], o[1], o[2], o[3]);
      *(float4*)(po + 4) = make_float4(o[4], o[5], o[6], o[7]);
      *(float4*)(po + 8) = make_float4(o[8], o[9], o[10], o[11]);
    }
  }
}

// ---------- phased gather: one src-range slab per kernel launch ----------
// FIRST: acc = self-loop; else acc = reload packed partial (slot 0 holds it).
template <int RW, bool FIRST>
__global__ void __launch_bounds__(BK, 8) k_gphase(
    const int* __restrict__ adj, const int* __restrict__ stA,
    const int* __restrict__ enB, const float* __restrict__ pin,
    float* __restrict__ accb, int n) {
  int g = blockIdx.x * blockDim.x + threadIdx.x;
  int i = g >> LOGS;
  int slot = g & (S - 1);
  if (i >= n) return;
  float acc[RW] = {};
  if (slot == 0) {
    if (FIRST) {
      typename RowT<RW>::T v = RowT<RW>::ld(pin + (size_t)i * RW);  // self-loop
      RowT<RW>::add(acc, v);
    } else {
      typename RowT<RW>::T v = RowT<RW>::ld(accb + (size_t)i * RW); // partial
      RowT<RW>::add(acc, v);
    }
  }
  gather_p<RW, 4>(adj, stA[i], enB[i], pin, acc, slot);
  group_reduce<RW>(acc);
  if (slot == 0) RowT<RW>::st(accb + (size_t)i * RW, acc);
}

// ---------- final phase: last slab + epilogue ----------
// MODE 1: l2norm+tanh -> pout (48B rows for FOUT=12)
// MODE 2: l2norm -> Wc -> l2norm -> out (13 floats)
template <int RW, int FOUT, int MODE>
__global__ void __launch_bounds__(BK, 6) k_gphase_last(
    const int* __restrict__ adj, const int* __restrict__ stA,
    const int* __restrict__ rowptr, const float* __restrict__ pin,
    const float* __restrict__ W, const float* __restrict__ bias,
    const float* __restrict__ Wc, const float* __restrict__ bc,
    const float* __restrict__ dinv, const float* __restrict__ accb,
    float* __restrict__ out, int n) {
  constexpr int FC = 13;
  __shared__ float sW[RW * FOUT];
  __shared__ float sb[FOUT];
  __shared__ float sWc[MODE == 2 ? FOUT * FC : 1];
  __shared__ float sbc[MODE == 2 ? FC : 1];
  for (int t = threadIdx.x; t < RW * FOUT; t += BK) sW[t] = W[t];
  if (threadIdx.x < FOUT) sb[threadIdx.x] = bias[threadIdx.x];
  if (MODE == 2) {
    for (int t = threadIdx.x; t < FOUT * FC; t += BK) sWc[t] = Wc[t];
    if (threadIdx.x < FC) sbc[threadIdx.x] = bc[threadIdx.x];
  }
  __syncthreads();
  int g = blockIdx.x * blockDim.x + threadIdx.x;
  int i = g >> LOGS;
  int slot = g & (S - 1);
  if (i >= n) return;
  float acc[RW] = {};
  if (slot == 0) {
    typename RowT<RW>::T v = RowT<RW>::ld(accb + (size_t)i * RW);   // partial
    RowT<RW>::add(acc, v);
  }
  gather_p<RW, 4>(adj, stA[i], rowptr[i + 1], pin, acc, slot);
  group_reduce<RW>(acc);
  float di = dinv[i];
  float h[FOUT];
  float ss = 0.f;
#pragma unroll
  for (int j = 0; j < FOUT; ++j) {
    float s = 0.f;
#pragma unroll
    for (int kk = 0; kk < RW; ++kk) s = fmaf(acc[kk], sW[kk * FOUT + j], s);
    float t = fmaf(di, s, sb[j]);
    h[j] = t;
    ss += t * t;
  }
  float inv = 1.f / fmaxf(sqrtf(ss), 1e-12f);
  if (MODE == 1) {
    float o[FOUT];
#pragma unroll
    for (int j = 0; j < FOUT; ++j) o[j] = di * tanhf(h[j] * inv);
    if (slot == 0) {
      float* po = out + (size_t)i * FOUT;                  // 48B rows (FOUT=12)
      *(float4*)(po)     = make_float4(o[0], o[1], o[2], o[3]);
      *(float4*)(po + 4) = make_float4(o[4], o[5], o[6], o[7]);
      *(float4*)(po + 8) = make_float4(o[8], o[9], o[10], o[11]);
    }
  } else {
    float v[FC];
    float ss2 = 0.f;
#pragma unroll
    for (int j = 0; j < FC; ++j) {
      float s = sbc[j];
#pragma unroll
      for (int kk = 0; kk < FOUT; ++kk) s = fmaf(h[kk] * inv, sWc[kk * FC + j], s);
      v[j] = s;
      ss2 += s * s;
    }
    float inv2 = 1.f / fmaxf(sqrtf(ss2), 1e-12f);
    if (slot == 0) {
#pragma unroll
      for (int j = 0; j < FC; ++j) out[(size_t)i * FC + j] = v[j] * inv2;
    }
  }
}

extern "C" void kernel_launch(void* const* d_in, const int* in_sizes, int n_in,
                              void* d_out, int out_size, void* d_ws, size_t ws_size,
                              hipStream_t stream) {
  const float* x  = (const float*)d_in[0];
  const int*   ei = (const int*)d_in[1];
  const float* W1 = (const float*)d_in[2];
  const float* b1 = (const float*)d_in[3];
  const float* W2 = (const float*)d_in[4];
  const float* b2 = (const float*)d_in[5];
  const float* W3 = (const float*)d_in[6];
  const float* b3 = (const float*)d_in[7];
  const float* Wc = (const float*)d_in[8];
  const float* bc = (const float*)d_in[9];
  float* out = (float*)d_out;

  const int n = NN;
  const int e = NE;
  const int* srcI = ei;       // row 0
  const int* dstI = ei + e;   // row 1

  // Workspace (words):
  //   dinv[N] | rowptr[N+8] | sbase[512] | tot[512] | hist[NBA*NBL] | adj[E]
  //   | b8[N] | b13[N] | b17[N] | pad->64B | R
  // R hosts dense stg[E]=6.4M words during build, then
  //   p1[3N] | p2[6N] | p3[12N] | accb[12N] (=6.6M words) during gathers.
  // hist = 391*1024 = 400384 words (1.6MB). Total ~= 58 MB (<=76 MB proven).
  float* ws = (float*)d_ws;
  float* dinv  = ws;
  int* rowptr  = (int*)(ws + n);            // N+8 (uses N+1, padded)
  int* sbase   = rowptr + n + 8;            // NBA+1 used
  int* tot     = sbase + 512;
  int* hist    = tot + 512;                 // NBA * NBL (16B-aligned)
  int* adj     = hist + NBA * NBL;
  int* b8      = adj + e;
  int* b13     = b8 + n;
  int* b17     = b13 + n;
  size_t roff = (size_t)n + (n + 8) + 512 + 512 + (size_t)NBA * NBL + e + 3 * (size_t)n;
  roff = (roff + 15) & ~(size_t)15;         // round to 16 words = 64B
  float* R     = ws + roff;
  unsigned* stg = (unsigned*)R;             // dense E words during build
  float* p1   = R;                          // 3N
  float* p2   = R + (size_t)3 * n;          // 6N
  float* p3   = R + (size_t)9 * n;          // 12N
  float* accb = R + (size_t)21 * n;         // 12N packed partials (16B-aligned)

  const int gn  = (n + BK - 1) / BK;
  const int gnS = (n * S + BK - 1) / BK;    // 3125 blocks

  // --- CSR build: count -> scan -> LDS-staged scatter -> half-bin 4-range build ---
  k_count<<<NBL, BKC, 0, stream>>>(dstI, hist, e);
  k_scanrow<<<NBA, 256, 0, stream>>>(hist, tot);
  k_scanbin<<<1, 512, 0, stream>>>(tot, sbase);
  k_scat<<<NBL, BKC, 0, stream>>>(srcI, dstI, hist, tot, sbase, stg, e);
  k_build<<<NBB, BKB, 0, stream>>>(stg, sbase, rowptr, adj, b8, b13, b17);

  // --- dinv + p1 = dinv * x (12B rows) ---
  k_prep<<<gn, BK, 0, stream>>>(x, rowptr, dinv, p1, n);

  // --- Layer 1 (p1 = 2.4 MB, fits per-XCD L2): single fused phase ---
  k_gather_fused<3, 6, 0><<<gnS, BK, 0, stream>>>(adj, rowptr, p1, W1, b1, dinv, p2, n);

  // --- Layer 2 (p2 = 4.8 MB): 2 phases, cut at b13 ---
  k_gphase<6, true><<<gnS, BK, 0, stream>>>(adj, rowptr, b13, p2, accb, n);
  k_gphase_last<6, 12, 1><<<gnS, BK, 0, stream>>>(adj, b13, rowptr, p2, W2, b2,
                                                  Wc, bc, dinv, accb, p3, n);

  // --- Layer 3 + classifier (p3 = 9.6 MB): 3 phases, cuts at b8/b17 ---
  k_gphase<12, true><<<gnS, BK, 0, stream>>>(adj, rowptr, b8, p3, accb, n);
  k_gphase<12, false><<<gnS, BK, 0, stream>>>(adj, b8, b17, p3, accb, n);
  k_gphase_last<12, 24, 2><<<gnS, BK, 0, stream>>>(adj, b17, rowptr, p3, W3, b3,
                                                   Wc, bc, dinv, accb, out, n);
}